// Round 1
// baseline (305.166 us; speedup 1.0000x reference)
//
#include <hip/hip_runtime.h>

// FourierFilter: per-(b,c) rfft-4096 -> top-k (80% energy) spectral mask -> irfft.
// x:[32,4096,128] f32. out = concat(x_var, x_inv), each [32,4096,128].
// Pipeline (2 kernels): per-series FFT/filter/iFFT reading x DIRECTLY via strided
// gathers (x is L3-resident; XCD-swizzled blocks keep each 64B line's 16 channel-blocks
// on one XCD so L2 absorbs the 16x line reuse), writing tiled buf -> finalize.
// buf layout TILED: buf[B][NT=64][C=128][TS=64] so filter writes and finalize reads
// are contiguous >=256B streams.

#define TLEN 4096
#define N2   2048
#define CCH  128
#define BB   32
#define NSER (BB * CCH)
#define HALF 16777216  // 32*4096*128
#define PI_F 3.14159265358979323846f
#define NT   64
#define TS   64
#define SLAB (CCH * TS)   // 8192 floats = 32KB per (b,tb) slab

// LDS pad swizzle for FFT arrays
#define LP(i) ((i) + ((i) >> 5))

__device__ __forceinline__ void cmul(float& r, float& i, float br, float bi) {
  float tr = r * br - i * bi;
  i = r * bi + i * br;
  r = tr;
}

__device__ __forceinline__ void dft4(float vr[4], float vi[4], float s) {
  float t0r = vr[0] + vr[2], t0i = vi[0] + vi[2];
  float t1r = vr[0] - vr[2], t1i = vi[0] - vi[2];
  float t2r = vr[1] + vr[3], t2i = vi[1] + vi[3];
  float d3r = vr[1] - vr[3], d3i = vi[1] - vi[3];
  float t3r = -s * d3i, t3i = s * d3r;
  vr[0] = t0r + t2r; vi[0] = t0i + t2i;
  vr[1] = t1r + t3r; vi[1] = t1i + t3i;
  vr[2] = t0r - t2r; vi[2] = t0i - t2i;
  vr[3] = t1r - t3r; vi[3] = t1i - t3i;
}

__device__ __forceinline__ void dft8(float vr[8], float vi[8], float s) {
  float er[4]  = {vr[0], vr[2], vr[4], vr[6]};
  float ei[4]  = {vi[0], vi[2], vi[4], vi[6]};
  float odr[4] = {vr[1], vr[3], vr[5], vr[7]};
  float odi[4] = {vi[1], vi[3], vi[5], vi[7]};
  dft4(er, ei, s);
  dft4(odr, odi, s);
  const float c = 0.70710678118654752440f;
  float wr[4] = {1.0f, c, 0.0f, -c};
  float wi[4] = {0.0f, s * c, s, s * c};
  #pragma unroll
  for (int k = 0; k < 4; ++k) {
    float tr = wr[k] * odr[k] - wi[k] * odi[k];
    float ti = wr[k] * odi[k] + wi[k] * odr[k];
    vr[k]     = er[k] + tr; vi[k]     = ei[k] + ti;
    vr[k + 4] = er[k] - tr; vi[k + 4] = ei[k] - ti;
  }
}

__device__ __forceinline__ void stage8_first(float* zr, float* zi, int tid, float s) {
  float vr[8], vi[8];
  #pragma unroll
  for (int r = 0; r < 8; ++r) {
    int idx = LP(tid + (r << 8));
    vr[r] = zr[idx]; vi[r] = zi[idx];
  }
  dft8(vr, vi, s);
  __syncthreads();
  #pragma unroll
  for (int r = 0; r < 8; ++r) {
    int idx = LP((tid << 3) + r);
    zr[idx] = vr[r]; zi[idx] = vi[r];
  }
  __syncthreads();
}

template <int NS>
__device__ __forceinline__ void stage8_tw(float* zr, float* zi, int tid, float s) {
  int j = tid;
  int p = j & (NS - 1);
  float vr[8], vi[8];
  #pragma unroll
  for (int r = 0; r < 8; ++r) {
    int idx = LP(j + (r << 8));
    vr[r] = zr[idx]; vi[r] = zi[idx];
  }
  float ang = s * 6.28318530717958647692f * (float)p / (float)(NS * 8);
  float s1, c1; __sincosf(ang, &s1, &c1);
  float c2 = c1 * c1 - s1 * s1, s2 = 2.0f * c1 * s1;
  float c3 = c2 * c1 - s2 * s1, s3 = c2 * s1 + s2 * c1;
  float c4 = c2 * c2 - s2 * s2, s4 = 2.0f * c2 * s2;
  float c5 = c4 * c1 - s4 * s1, s5 = c4 * s1 + s4 * c1;
  float c6 = c4 * c2 - s4 * s2, s6 = c4 * s2 + s4 * c2;
  float c7 = c4 * c3 - s4 * s3, s7 = c4 * s3 + s4 * c3;
  cmul(vr[1], vi[1], c1, s1);
  cmul(vr[2], vi[2], c2, s2);
  cmul(vr[3], vi[3], c3, s3);
  cmul(vr[4], vi[4], c4, s4);
  cmul(vr[5], vi[5], c5, s5);
  cmul(vr[6], vi[6], c6, s6);
  cmul(vr[7], vi[7], c7, s7);
  dft8(vr, vi, s);
  __syncthreads();
  int idxD = ((j - p) << 3) + p;
  #pragma unroll
  for (int r = 0; r < 8; ++r) {
    int idx = LP(idxD + r * NS);
    zr[idx] = vr[r]; zi[idx] = vi[r];
  }
  __syncthreads();
}

__device__ __forceinline__ void stage4_last(float* zr, float* zi, int tid, float s) {
  #pragma unroll
  for (int half = 0; half < 2; ++half) {
    int j = tid + (half << 8);
    float ang = s * PI_F * (float)j * (1.0f / 1024.0f);
    float s1, c1; __sincosf(ang, &s1, &c1);
    float c2 = c1 * c1 - s1 * s1, s2 = 2.0f * c1 * s1;
    float c3 = c2 * c1 - s2 * s1, s3 = c2 * s1 + s2 * c1;
    float vr[4], vi[4];
    #pragma unroll
    for (int r = 0; r < 4; ++r) {
      int idx = LP(j + (r << 9));
      vr[r] = zr[idx]; vi[r] = zi[idx];
    }
    cmul(vr[1], vi[1], c1, s1);
    cmul(vr[2], vi[2], c2, s2);
    cmul(vr[3], vi[3], c3, s3);
    dft4(vr, vi, s);
    #pragma unroll
    for (int r = 0; r < 4; ++r) {
      int idx = LP(j + (r << 9));
      zr[idx] = vr[r]; zi[idx] = vi[r];
    }
  }
  __syncthreads();
}

__device__ __forceinline__ void fft2048(float* zr, float* zi, int tid, float s) {
  stage8_first(zr, zi, tid, s);
  stage8_tw<8>(zr, zi, tid, s);
  stage8_tw<64>(zr, zi, tid, s);
  stage4_last(zr, zi, tid, s);
}

__device__ __forceinline__ float block_sum(float v, float* red, int tid, int bank) {
  #pragma unroll
  for (int o = 32; o > 0; o >>= 1) v += __shfl_down(v, o, 64);
  if ((tid & 63) == 0) red[(bank << 2) + (tid >> 6)] = v;
  __syncthreads();
  int b4 = bank << 2;
  return red[b4] + red[b4 + 1] + red[b4 + 2] + red[b4 + 3];
}

// One block (256 thr) per series, reading x directly (strided gather, L2/L3-resident).
__global__ __launch_bounds__(256, 8) void fourier_filter_series(const float* __restrict__ x,
                                                                float* __restrict__ buf) {
  __shared__ float zr[2113], zi[2113];
  __shared__ float red[8];
  int tid = threadIdx.x;

  // XCD-aware swizzle: HW round-robins blockIdx across 8 XCDs; map so that the 16
  // channel-blocks sharing each 64B x-line (same b, c-group of 16) land on ONE XCD.
  int bid = blockIdx.x;
  int r = bid & 7;           // XCD under round-robin dispatch
  int m = bid >> 3;          // 0..511
  int b = m >> 4;            // 0..31
  int u = m & 15;            // channel-within-group
  int c = (((r + b) & 7) << 4) | u;

  // Gather-load series (b,c): element t at x[(b*4096+t)*128 + c], stride 512B.
  // Two 4-deep batches keep 8 loads in flight without blowing the 64-VGPR budget.
  const float* xp = x + ((size_t)b * TLEN) * CCH + c;
  #pragma unroll
  for (int jb = 0; jb < 2; ++jb) {
    float re[4], im[4];
    #pragma unroll
    for (int j = 0; j < 4; ++j) {
      int k = tid + (((jb << 2) + j) << 8);
      int off = k << 8;                 // (2k)*CCH
      re[j] = xp[off];
      im[j] = xp[off + CCH];
    }
    #pragma unroll
    for (int j = 0; j < 4; ++j) {
      int k = tid + (((jb << 2) + j) << 8);
      zr[LP(k)] = re[j];
      zi[LP(k)] = im[j];
    }
  }
  __syncthreads();

  fft2048(zr, zi, tid, -1.0f);   // forward

  // Unpack to rfft bins X[0..2048] IN PLACE (per-thread pairs (k,2048-k)); energies in regs.
  float eb[9];
  eb[8] = 0.0f;
  const float RC  = 0.92387953251128675613f;   // cos(pi/8)
  const float RSn = -0.38268343236508977173f;  // -sin(pi/8)
  float ws, wc;
  __sincosf(-PI_F * (float)tid * (1.0f / 2048.0f), &ws, &wc);
  #pragma unroll
  for (int jj = 0; jj < 4; ++jj) {
    int k = tid + (jj << 8);
    int mkz = (N2 - k) & (N2 - 1);
    int ik = LP(k), im = LP(N2 - k);
    float akr = zr[ik],      aki = zi[ik];
    float bkr = zr[LP(mkz)], bki = zi[LP(mkz)];
    float Er  = 0.5f * (akr + bkr);
    float Ei  = 0.5f * (aki - bki);
    float Or_ = 0.5f * (aki + bki);
    float Oi  = 0.5f * (bkr - akr);
    float tr = wc * Or_ - ws * Oi;
    float ti = wc * Oi + ws * Or_;
    float x0r = Er + tr, x0i = Ei + ti;
    float x1r = Er - tr, x1i = ti - Ei;
    zr[ik] = x0r; zi[ik] = x0i;
    zr[im] = x1r; zi[im] = x1i;
    eb[2 * jj]     = x0r * x0r + x0i * x0i;
    eb[2 * jj + 1] = x1r * x1r + x1i * x1i;
    float nwc = wc * RC - ws * RSn;
    ws = wc * RSn + ws * RC; wc = nwc;
  }
  if (tid == 0) {
    int i4 = LP(1024);
    float re = zr[i4], im_ = zi[i4];
    zi[i4] = -im_;
    eb[8] = re * re + im_ * im_;
  }

  // Selection: tau = max tau s.t. sum(e >= tau) > 0.8*total.
  float tloc = 0.0f;
  #pragma unroll
  for (int s = 0; s < 9; ++s) tloc += eb[s];
  float total = block_sum(tloc, red, tid, 0);
  float thresh = 0.8f * total;

  unsigned lo = 0u, hi = 0x7F7FFFFFu;
  for (int it = 0; it < 31; ++it) {
    unsigned mid = (lo + hi + 1u) >> 1;
    float tau = __uint_as_float(mid);
    float loc = 0.0f;
    #pragma unroll
    for (int s = 0; s < 9; ++s) loc += (eb[s] >= tau) ? eb[s] : 0.0f;
    float ssum = block_sum(loc, red, tid, (it + 1) & 1);
    if (ssum > thresh) lo = mid; else hi = mid - 1;
  }
  float tau = __uint_as_float(lo);

  // Mask + hermitian repack IN PLACE.
  const float RSp = 0.38268343236508977173f;
  __sincosf(PI_F * (float)tid * (1.0f / 2048.0f), &ws, &wc);
  #pragma unroll
  for (int jj = 0; jj < 4; ++jj) {
    int k = tid + (jj << 8);
    int ik = LP(k), im = LP(N2 - k);
    float xkr = zr[ik], xki = zi[ik];
    float xmr = zr[im], xmi = zi[im];
    float ekk = xkr * xkr + xki * xki;
    float emm = xmr * xmr + xmi * xmi;
    if (ekk >= tau) { xkr = 0.0f; xki = 0.0f; }
    if (emm >= tau) { xmr = 0.0f; xmi = 0.0f; }
    float Er = 0.5f * (xkr + xmr);
    float Ei = 0.5f * (xki - xmi);
    float Br = 0.5f * (xkr - xmr);
    float Bi = 0.5f * (xki + xmi);
    float Or_ = wc * Br - ws * Bi;
    float Oi  = wc * Bi + ws * Br;
    zr[ik] = Er - Oi;  zi[ik] = Ei + Or_;
    zr[im] = Er + Oi;  zi[im] = Or_ - Ei;
    float nwc = wc * RC - ws * RSp;
    ws = wc * RSp + ws * RC; wc = nwc;
  }
  if (tid == 0) {
    int i4 = LP(1024);
    float re = zr[i4], im_ = zi[i4];
    float e = re * re + im_ * im_;
    if (e >= tau) { re = 0.0f; im_ = 0.0f; }
    zr[i4] = re; zi[i4] = -im_;
  }
  __syncthreads();

  fft2048(zr, zi, tid, 1.0f);    // inverse (unscaled)

  // Write filtered series to tiled buf (contiguous 256B streams).
  float* bufp = buf + (size_t)b * (NT * SLAB) + (size_t)c * TS;
  const float scale = 1.0f / 2048.0f;
  #pragma unroll
  for (int j = 0; j < 8; ++j) {
    int k = tid + (j << 8);
    int off = ((k >> 5) << 13) + ((k & 31) << 1);
    float2 v;
    v.x = zr[LP(k)] * scale;
    v.y = zi[LP(k)] * scale;
    *(float2*)(bufp + off) = v;
  }
}

// buf[B][NT][C][TS] + x[B,T,C] -> xvar[B,T,C], xinv = x - xvar.
// Block (tb,b): read 32KB contiguous slab, write full coalesced rows.
// LDS layout XOR-swizzled on c with key (row>>2)&7: store path 2-way (free) instead
// of the previous 8-way bank conflict; float4 read path stays 4-way, alignment kept.
// NOTE: safe when buf aliases xinv (block's slab == block's xinv range; reads precede writes).
__global__ __launch_bounds__(512) void finalize_t(const float* __restrict__ buf, const float* __restrict__ x,
                                                  float* __restrict__ xvar, float* __restrict__ xinv) {
  __shared__ float lds[TS * 132];   // lds[t*132 + (c ^ key(t))]
  int tb = blockIdx.x, b = blockIdx.y;
  const float* ip = buf + ((size_t)b * NT + tb) * SLAB;
  #pragma unroll
  for (int it = 0; it < 4; ++it) {
    int idx = threadIdx.x + (it << 9);
    int c = idx >> 4, s4 = (idx & 15) << 2;
    float4 v = *(const float4*)(ip + c * TS + s4);
    int cs = c ^ (s4 & 28);         // key = ((row>>2)&7)<<2, rows s4..s4+3 share it
    lds[(s4 + 0) * 132 + cs] = v.x;
    lds[(s4 + 1) * 132 + cs] = v.y;
    lds[(s4 + 2) * 132 + cs] = v.z;
    lds[(s4 + 3) * 132 + cs] = v.w;
  }
  __syncthreads();
  size_t rowbase = ((size_t)b * TLEN + (size_t)tb * TS) * CCH;
  #pragma unroll
  for (int it = 0; it < 4; ++it) {
    int idx = threadIdx.x + (it << 9);
    int t = idx >> 5, c4 = (idx & 31) << 2;
    int key = ((t >> 2) & 7) << 2;
    float4 v = *(const float4*)(&lds[t * 132 + (c4 ^ key)]);
    size_t off = rowbase + (size_t)t * CCH + c4;
    float4 xv = *(const float4*)(x + off);
    *(float4*)(xvar + off) = v;
    *(float4*)(xinv + off) = make_float4(xv.x - v.x, xv.y - v.y, xv.z - v.z, xv.w - v.w);
  }
}

extern "C" void kernel_launch(void* const* d_in, const int* in_sizes, int n_in,
                              void* d_out, int out_size, void* d_ws, size_t ws_size,
                              hipStream_t stream) {
  const float* x = (const float*)d_in[0];
  float* out  = (float*)d_out;
  float* xvar = out;
  float* xinv = out + HALF;

  bool use_ws = ws_size >= (size_t)HALF * sizeof(float);
  float* buf = use_ws ? (float*)d_ws : xinv;   // fallback: stage tiled buf in x_inv region (aliasing-safe)

  fourier_filter_series<<<NSER, 256, 0, stream>>>(x, buf);
  dim3 tgrid(NT, BB);
  finalize_t<<<tgrid, 512, 0, stream>>>(buf, x, xvar, xinv);
}

// Round 2
// 290.595 us; speedup vs baseline: 1.0501x; 1.0501x over previous
//
#include <hip/hip_runtime.h>

// FourierFilter: per-(b,c) rfft-4096 -> top-k (80% energy) spectral mask -> irfft.
// x:[32,4096,128] f32. out = concat(x_var, x_inv), each [32,4096,128].
// SINGLE fused kernel: one 1024-thread block handles 4 ADJACENT channels of one batch
// (4 independent 256-thread FFT "groups" sharing the block's barriers). All global
// traffic is float4 (16B/lane): load x -> 4 series in LDS, FFT/filter/iFFT in LDS,
// write xvar and xinv=x-xvar directly. No intermediate buffer, no finalize kernel.
// XCD swizzle keeps the 4 blocks sharing each 64B x/out line (same b, same 16-channel
// line-group) dispatch-adjacent on one XCD so L2 combines the strided reads AND writes.

#define TLEN 4096
#define N2   2048
#define CCH  128
#define BB   32
#define HALF 16777216  // 32*4096*128
#define PI_F 3.14159265358979323846f

// LDS pad swizzle for FFT arrays
#define LP(i) ((i) + ((i) >> 5))
#define ZLEN 2113      // LP(2048) + safety

__device__ __forceinline__ void cmul(float& r, float& i, float br, float bi) {
  float tr = r * br - i * bi;
  i = r * bi + i * br;
  r = tr;
}

__device__ __forceinline__ void dft4(float vr[4], float vi[4], float s) {
  float t0r = vr[0] + vr[2], t0i = vi[0] + vi[2];
  float t1r = vr[0] - vr[2], t1i = vi[0] - vi[2];
  float t2r = vr[1] + vr[3], t2i = vi[1] + vi[3];
  float d3r = vr[1] - vr[3], d3i = vi[1] - vi[3];
  float t3r = -s * d3i, t3i = s * d3r;
  vr[0] = t0r + t2r; vi[0] = t0i + t2i;
  vr[1] = t1r + t3r; vi[1] = t1i + t3i;
  vr[2] = t0r - t2r; vi[2] = t0i - t2i;
  vr[3] = t1r - t3r; vi[3] = t1i - t3i;
}

__device__ __forceinline__ void dft8(float vr[8], float vi[8], float s) {
  float er[4]  = {vr[0], vr[2], vr[4], vr[6]};
  float ei[4]  = {vi[0], vi[2], vi[4], vi[6]};
  float odr[4] = {vr[1], vr[3], vr[5], vr[7]};
  float odi[4] = {vi[1], vi[3], vi[5], vi[7]};
  dft4(er, ei, s);
  dft4(odr, odi, s);
  const float c = 0.70710678118654752440f;
  float wr[4] = {1.0f, c, 0.0f, -c};
  float wi[4] = {0.0f, s * c, s, s * c};
  #pragma unroll
  for (int k = 0; k < 4; ++k) {
    float tr = wr[k] * odr[k] - wi[k] * odi[k];
    float ti = wr[k] * odi[k] + wi[k] * odr[k];
    vr[k]     = er[k] + tr; vi[k]     = ei[k] + ti;
    vr[k + 4] = er[k] - tr; vi[k + 4] = ei[k] - ti;
  }
}

__device__ __forceinline__ void stage8_first(float* zr, float* zi, int tid, float s) {
  float vr[8], vi[8];
  #pragma unroll
  for (int r = 0; r < 8; ++r) {
    int idx = LP(tid + (r << 8));
    vr[r] = zr[idx]; vi[r] = zi[idx];
  }
  dft8(vr, vi, s);
  __syncthreads();
  #pragma unroll
  for (int r = 0; r < 8; ++r) {
    int idx = LP((tid << 3) + r);
    zr[idx] = vr[r]; zi[idx] = vi[r];
  }
  __syncthreads();
}

template <int NS>
__device__ __forceinline__ void stage8_tw(float* zr, float* zi, int tid, float s) {
  int j = tid;
  int p = j & (NS - 1);
  float vr[8], vi[8];
  #pragma unroll
  for (int r = 0; r < 8; ++r) {
    int idx = LP(j + (r << 8));
    vr[r] = zr[idx]; vi[r] = zi[idx];
  }
  float ang = s * 6.28318530717958647692f * (float)p / (float)(NS * 8);
  float s1, c1; __sincosf(ang, &s1, &c1);
  float c2 = c1 * c1 - s1 * s1, s2 = 2.0f * c1 * s1;
  float c3 = c2 * c1 - s2 * s1, s3 = c2 * s1 + s2 * c1;
  float c4 = c2 * c2 - s2 * s2, s4 = 2.0f * c2 * s2;
  float c5 = c4 * c1 - s4 * s1, s5 = c4 * s1 + s4 * c1;
  float c6 = c4 * c2 - s4 * s2, s6 = c4 * s2 + s4 * c2;
  float c7 = c4 * c3 - s4 * s3, s7 = c4 * s3 + s4 * c3;
  cmul(vr[1], vi[1], c1, s1);
  cmul(vr[2], vi[2], c2, s2);
  cmul(vr[3], vi[3], c3, s3);
  cmul(vr[4], vi[4], c4, s4);
  cmul(vr[5], vi[5], c5, s5);
  cmul(vr[6], vi[6], c6, s6);
  cmul(vr[7], vi[7], c7, s7);
  dft8(vr, vi, s);
  __syncthreads();
  int idxD = ((j - p) << 3) + p;
  #pragma unroll
  for (int r = 0; r < 8; ++r) {
    int idx = LP(idxD + r * NS);
    zr[idx] = vr[r]; zi[idx] = vi[r];
  }
  __syncthreads();
}

__device__ __forceinline__ void stage4_last(float* zr, float* zi, int tid, float s) {
  #pragma unroll
  for (int half = 0; half < 2; ++half) {
    int j = tid + (half << 8);
    float ang = s * PI_F * (float)j * (1.0f / 1024.0f);
    float s1, c1; __sincosf(ang, &s1, &c1);
    float c2 = c1 * c1 - s1 * s1, s2 = 2.0f * c1 * s1;
    float c3 = c2 * c1 - s2 * s1, s3 = c2 * s1 + s2 * c1;
    float vr[4], vi[4];
    #pragma unroll
    for (int r = 0; r < 4; ++r) {
      int idx = LP(j + (r << 9));
      vr[r] = zr[idx]; vi[r] = zi[idx];
    }
    cmul(vr[1], vi[1], c1, s1);
    cmul(vr[2], vi[2], c2, s2);
    cmul(vr[3], vi[3], c3, s3);
    dft4(vr, vi, s);
    #pragma unroll
    for (int r = 0; r < 4; ++r) {
      int idx = LP(j + (r << 9));
      zr[idx] = vr[r]; zi[idx] = vi[r];
    }
  }
  __syncthreads();
}

__device__ __forceinline__ void fft2048(float* zr, float* zi, int tid, float s) {
  stage8_first(zr, zi, tid, s);
  stage8_tw<8>(zr, zi, tid, s);
  stage8_tw<64>(zr, zi, tid, s);
  stage4_last(zr, zi, tid, s);
}

// Group-level (256-thread) reduction inside a 1024-thread block; all threads call it.
__device__ __forceinline__ float group_sum(float v, float* redg, int tg, int bank) {
  #pragma unroll
  for (int o = 32; o > 0; o >>= 1) v += __shfl_down(v, o, 64);
  if ((tg & 63) == 0) redg[(bank << 2) + (tg >> 6)] = v;
  __syncthreads();
  int b4 = bank << 2;
  return redg[b4] + redg[b4 + 1] + redg[b4 + 2] + redg[b4 + 3];
}

// One 1024-thread block per (batch b, channel-quad cg): 4 independent FFT groups.
__global__ __launch_bounds__(1024, 8) void fourier_filter_fused(const float* __restrict__ x,
                                                                float* __restrict__ xvar,
                                                                float* __restrict__ xinv) {
  // z[0]=real planes, z[1]=imag planes; plane g = series for channel cbase+g.
  __shared__ float z[2][4][ZLEN];
  __shared__ float red[64];   // 8 floats per group (2 banks x 4 waves), 4 groups

  int tidx = threadIdx.x;

  // XCD swizzle: bid = m*8 + r round-robins r across XCDs. Decompose m so the 4
  // blocks sharing each 64B line (same b, same line-group lg, ql=0..3) are
  // m-consecutive on the same XCD r, and lg rotates with (r+b) for balance.
  int bid = blockIdx.x;
  int r = bid & 7;            // XCD under round-robin dispatch
  int m = bid >> 3;           // 0..127
  int b = m >> 2;             // 0..31
  int ql = m & 3;             // quad-within-line-group
  int cg = (((r + b) & 7) << 2) | ql;   // channel-quad 0..31
  int cbase = cg << 2;

  const float* xp = x + (size_t)b * (TLEN * CCH) + cbase;

  // ---- Load: thread covers time t; float4 spans the block's 4 channels. ----
  #pragma unroll
  for (int it = 0; it < 4; ++it) {
    int t = tidx + (it << 10);
    float4 v = *(const float4*)(xp + (size_t)t * CCH);
    float* dst = &z[t & 1][0][0];           // parity -> real/imag plane (no branch)
    int k = LP(t >> 1);
    dst[k]            = v.x;
    dst[ZLEN + k]     = v.y;
    dst[2 * ZLEN + k] = v.z;
    dst[3 * ZLEN + k] = v.w;
  }
  __syncthreads();

  int g  = tidx >> 8;         // FFT group = channel within quad
  int tg = tidx & 255;        // thread-in-group
  float* Zr = z[0][g];
  float* Zi = z[1][g];
  float* redg = red + (g << 3);

  fft2048(Zr, Zi, tg, -1.0f);   // forward

  // ---- Unpack to rfft bins X[0..2048] IN PLACE; energies in regs. ----
  float eb[9];
  eb[8] = 0.0f;
  const float RC  = 0.92387953251128675613f;   // cos(pi/8)
  const float RSn = -0.38268343236508977173f;  // -sin(pi/8)
  float ws, wc;
  __sincosf(-PI_F * (float)tg * (1.0f / 2048.0f), &ws, &wc);
  #pragma unroll
  for (int jj = 0; jj < 4; ++jj) {
    int k = tg + (jj << 8);
    int mkz = (N2 - k) & (N2 - 1);
    int ik = LP(k), im = LP(N2 - k);
    float akr = Zr[ik],      aki = Zi[ik];
    float bkr = Zr[LP(mkz)], bki = Zi[LP(mkz)];
    float Er  = 0.5f * (akr + bkr);
    float Ei  = 0.5f * (aki - bki);
    float Or_ = 0.5f * (aki + bki);
    float Oi  = 0.5f * (bkr - akr);
    float tr = wc * Or_ - ws * Oi;
    float ti = wc * Oi + ws * Or_;
    float x0r = Er + tr, x0i = Ei + ti;
    float x1r = Er - tr, x1i = ti - Ei;
    Zr[ik] = x0r; Zi[ik] = x0i;
    Zr[im] = x1r; Zi[im] = x1i;
    eb[2 * jj]     = x0r * x0r + x0i * x0i;
    eb[2 * jj + 1] = x1r * x1r + x1i * x1i;
    float nwc = wc * RC - ws * RSn;
    ws = wc * RSn + ws * RC; wc = nwc;
  }
  if (tg == 0) {
    int i4 = LP(1024);
    float re = Zr[i4], im_ = Zi[i4];
    Zi[i4] = -im_;
    eb[8] = re * re + im_ * im_;
  }

  // ---- Selection: tau = max tau s.t. sum(e >= tau) > 0.8*total (per group). ----
  float tloc = 0.0f;
  #pragma unroll
  for (int s = 0; s < 9; ++s) tloc += eb[s];
  float total = group_sum(tloc, redg, tg, 0);
  float thresh = 0.8f * total;

  unsigned lo = 0u, hi = 0x7F7FFFFFu;
  for (int it = 0; it < 31; ++it) {
    unsigned mid = (lo + hi + 1u) >> 1;
    float tau = __uint_as_float(mid);
    float loc = 0.0f;
    #pragma unroll
    for (int s = 0; s < 9; ++s) loc += (eb[s] >= tau) ? eb[s] : 0.0f;
    float ssum = group_sum(loc, redg, tg, (it + 1) & 1);
    if (ssum > thresh) lo = mid; else hi = mid - 1;
  }
  float tau = __uint_as_float(lo);

  // ---- Mask + hermitian repack IN PLACE. ----
  const float RSp = 0.38268343236508977173f;
  __sincosf(PI_F * (float)tg * (1.0f / 2048.0f), &ws, &wc);
  #pragma unroll
  for (int jj = 0; jj < 4; ++jj) {
    int k = tg + (jj << 8);
    int ik = LP(k), im = LP(N2 - k);
    float xkr = Zr[ik], xki = Zi[ik];
    float xmr = Zr[im], xmi = Zi[im];
    float ekk = xkr * xkr + xki * xki;
    float emm = xmr * xmr + xmi * xmi;
    if (ekk >= tau) { xkr = 0.0f; xki = 0.0f; }
    if (emm >= tau) { xmr = 0.0f; xmi = 0.0f; }
    float Er = 0.5f * (xkr + xmr);
    float Ei = 0.5f * (xki - xmi);
    float Br = 0.5f * (xkr - xmr);
    float Bi = 0.5f * (xki + xmi);
    float Or_ = wc * Br - ws * Bi;
    float Oi  = wc * Bi + ws * Br;
    Zr[ik] = Er - Oi;  Zi[ik] = Ei + Or_;
    Zr[im] = Er + Oi;  Zi[im] = Or_ - Ei;
    float nwc = wc * RC - ws * RSp;
    ws = wc * RSp + ws * RC; wc = nwc;
  }
  if (tg == 0) {
    int i4 = LP(1024);
    float re = Zr[i4], im_ = Zi[i4];
    float e = re * re + im_ * im_;
    if (e >= tau) { re = 0.0f; im_ = 0.0f; }
    Zr[i4] = re; Zi[i4] = -im_;
  }
  __syncthreads();

  fft2048(Zr, Zi, tg, 1.0f);    // inverse (unscaled); ends with __syncthreads()

  // ---- Store: xvar float4 across the 4 channels; xinv = x - xvar. ----
  const float scale = 1.0f / 2048.0f;
  size_t base = (size_t)b * (TLEN * CCH) + cbase;
  #pragma unroll
  for (int it = 0; it < 4; ++it) {
    int t = tidx + (it << 10);
    const float* src = &z[t & 1][0][0];
    int k = LP(t >> 1);
    float4 v;
    v.x = src[k]            * scale;
    v.y = src[ZLEN + k]     * scale;
    v.z = src[2 * ZLEN + k] * scale;
    v.w = src[3 * ZLEN + k] * scale;
    size_t off = base + (size_t)t * CCH;
    float4 xv = *(const float4*)(x + off);
    *(float4*)(xvar + off) = v;
    *(float4*)(xinv + off) = make_float4(xv.x - v.x, xv.y - v.y, xv.z - v.z, xv.w - v.w);
  }
}

extern "C" void kernel_launch(void* const* d_in, const int* in_sizes, int n_in,
                              void* d_out, int out_size, void* d_ws, size_t ws_size,
                              hipStream_t stream) {
  const float* x = (const float*)d_in[0];
  float* out  = (float*)d_out;
  float* xvar = out;
  float* xinv = out + HALF;

  (void)d_ws; (void)ws_size;
  fourier_filter_fused<<<BB * 32, 1024, 0, stream>>>(x, xvar, xinv);
}